// Round 1
// baseline (130.608 us; speedup 1.0000x reference)
//
#include <hip/hip_runtime.h>
#include <stdint.h>

#define IN_F 2048
#define OUT_F 2048
#define N_ROWS 8192

#define BM 128
#define BN 128
#define BK 32
#define TN_TILES (OUT_F / BN)      // 16
#define TM_TILES (N_ROWS / BM)     // 64
#define NWG (TM_TILES * TN_TILES)  // 1024

typedef __bf16 bf16x8 __attribute__((ext_vector_type(8)));
typedef float f32x4 __attribute__((ext_vector_type(4)));
typedef unsigned short ushortx8 __attribute__((ext_vector_type(8)));

// fp32 -> bf16 bits, round-to-nearest-even (bit trick; inputs are finite randoms)
__device__ __forceinline__ unsigned short f2bf(float f) {
  unsigned u = __builtin_bit_cast(unsigned, f);
  u += 0x7FFFu + ((u >> 16) & 1u);
  return (unsigned short)(u >> 16);
}

// async global->LDS, 16B per lane. LDS dest must be wave-uniform base + lane*16.
__device__ __forceinline__ void async16(void* lds, const void* g) {
  __builtin_amdgcn_global_load_lds(
      (const __attribute__((address_space(1))) void*)(uintptr_t)g,
      (__attribute__((address_space(3))) void*)(uint32_t)(uintptr_t)lds,
      16, 0, 0);
}

// ---- prep 1: A (fp32 [8192][2048]) -> bf16 bits ----
__global__ __launch_bounds__(256) void k_convertA(const float* __restrict__ A,
                                                  unsigned short* __restrict__ Ab) {
  const size_t t = (size_t)blockIdx.x * 256 + threadIdx.x;  // 2,097,152 threads x 8 elems
  const float4* a4 = reinterpret_cast<const float4*>(A);
  float4 v0 = a4[2 * t];
  float4 v1 = a4[2 * t + 1];
  ushortx8 o;
  o[0] = f2bf(v0.x); o[1] = f2bf(v0.y); o[2] = f2bf(v0.z); o[3] = f2bf(v0.w);
  o[4] = f2bf(v1.x); o[5] = f2bf(v1.y); o[6] = f2bf(v1.z); o[7] = f2bf(v1.w);
  *reinterpret_cast<ushortx8*>(Ab + t * 8) = o;
}

// ---- prep 2: Ht[b][a] = H_perm[a][b] = s(q,c) * W[u][(q^c)*512 + v] ----
// q=a&3, u=a>>2, c=b&3, v=b>>2 ; sign mask 0x284E indexed by q*4+c (1 => negate)
__global__ __launch_bounds__(256) void k_buildHt(const float* __restrict__ W,
                                                 unsigned short* __restrict__ Ht) {
  const int t = blockIdx.x * 256 + threadIdx.x;  // 524,288 threads x 8 elems
  const int b = t >> 8;                          // 256 threads per Ht row
  const int a0 = (t & 255) << 3;
  const int c = b & 3, v = b >> 2;
  ushortx8 o;
#pragma unroll
  for (int e = 0; e < 8; ++e) {
    const int a = a0 + e;
    const int q = a & 3, u = a >> 2;
    float w = W[(size_t)u * OUT_F + ((q ^ c) << 9) + v];
    if ((0x284E >> ((q << 2) | c)) & 1) w = -w;
    o[e] = f2bf(w);
  }
  *reinterpret_cast<ushortx8*>(Ht + (size_t)b * IN_F + a0) = o;
}

// ---- main GEMM: C[8192][2048] = Abf16 @ Ht^T + bias (m97 structure) ----
__global__ __launch_bounds__(256) void k_gemm(const unsigned short* __restrict__ A,
                                              const unsigned short* __restrict__ Bt,
                                              const float* __restrict__ bias,
                                              float* __restrict__ C) {
  __shared__ __align__(16) unsigned short sA[BM * BK];  // [128][32] bf16, 8KB
  __shared__ __align__(16) unsigned short sB[BN * BK];  // [128][32] bf16, 8KB

  const int tid = threadIdx.x;
  const int lane = tid & 63;
  const int wr = (tid >> 6) >> 1;  // wave row 0..1
  const int wc = (tid >> 6) & 1;   // wave col 0..1

  // XCD-bijective swizzle (NWG=1024, %8==0): each XCD gets 128 consecutive tiles
  const int wg = blockIdx.x;
  const int swz = (wg & 7) * (NWG >> 3) + (wg >> 3);
  const int tn = swz & (TN_TILES - 1);
  const int tm = swz >> 4;  // / TN_TILES

  const int row0 = tm * BM;
  const int col0 = tn * BN;

  // staging: chunk p (16B) -> LDS byte p*16 ; tile row r = p>>2, col (p&3)*8
  const int r0 = tid >> 2;
  const int kk0 = (tid & 3) << 3;
  const unsigned short* gA0 = A + (size_t)(row0 + r0) * IN_F + kk0;
  const unsigned short* gB0 = Bt + (size_t)(col0 + r0) * IN_F + kk0;
  unsigned short* lA0 = &sA[tid * 8];
  unsigned short* lA1 = &sA[(tid + 256) * 8];
  unsigned short* lB0 = &sB[tid * 8];
  unsigned short* lB1 = &sB[(tid + 256) * 8];
  const size_t rowskip = (size_t)64 * IN_F;  // second call covers rows 64..127

  f32x4 acc[4][4] = {};

  const int ko = (lane >> 4) << 3;  // k offset 0,8,16,24
  const int fr = lane & 15;         // fragment row/col index

  for (int kt = 0; kt < IN_F; kt += BK) {
    async16(lA0, gA0 + kt);
    async16(lA1, gA0 + rowskip + kt);
    async16(lB0, gB0 + kt);
    async16(lB1, gB0 + rowskip + kt);
    __syncthreads();  // compiler drains vmcnt before s_barrier

    bf16x8 af[4], bfr[4];
#pragma unroll
    for (int m = 0; m < 4; ++m) {
      const int r = wr * 64 + m * 16 + fr;
      af[m] = __builtin_bit_cast(bf16x8,
          *reinterpret_cast<const ushortx8*>(&sA[r * BK + ko]));
    }
#pragma unroll
    for (int n = 0; n < 4; ++n) {
      const int r = wc * 64 + n * 16 + fr;
      bfr[n] = __builtin_bit_cast(bf16x8,
          *reinterpret_cast<const ushortx8*>(&sB[r * BK + ko]));
    }
#pragma unroll
    for (int m = 0; m < 4; ++m)
#pragma unroll
      for (int n = 0; n < 4; ++n)
        acc[m][n] = __builtin_amdgcn_mfma_f32_16x16x32_bf16(af[m], bfr[n],
                                                            acc[m][n], 0, 0, 0);
    __syncthreads();
  }

  // epilogue: C/D layout col=lane&15, row=(lane>>4)*4+reg
  const int g4 = (lane >> 4) << 2;
  float bv[4];
#pragma unroll
  for (int n = 0; n < 4; ++n) bv[n] = bias[col0 + wc * 64 + n * 16 + fr];
#pragma unroll
  for (int m = 0; m < 4; ++m) {
#pragma unroll
    for (int e = 0; e < 4; ++e) {
      const int row = row0 + wr * 64 + m * 16 + g4 + e;
      float* cp = C + (size_t)row * OUT_F + col0 + wc * 64 + fr;
#pragma unroll
      for (int n = 0; n < 4; ++n)
        cp[n * 16] = acc[m][n][e] + bv[n];
    }
  }
}

// ---- fallback if workspace is too small: naive fp32 (slow but correct) ----
__global__ __launch_bounds__(256) void k_naive(const float* __restrict__ A,
                                               const float* __restrict__ W,
                                               const float* __restrict__ bias,
                                               float* __restrict__ C) {
  const int idx = blockIdx.x * 256 + threadIdx.x;
  const int m = idx >> 11;           // / OUT_F
  const int b = idx & (OUT_F - 1);
  const int c = b & 3, v = b >> 2;
  float acc = 0.f;
  const float* arow = A + (size_t)m * IN_F;
  for (int a = 0; a < IN_F; ++a) {
    const int q = a & 3, u = a >> 2;
    float h = W[(size_t)u * OUT_F + ((q ^ c) << 9) + v];
    if ((0x284E >> ((q << 2) | c)) & 1) h = -h;
    acc += arow[a] * h;
  }
  C[idx] = acc + bias[b];
}

extern "C" void kernel_launch(void* const* d_in, const int* in_sizes, int n_in,
                              void* d_out, int out_size, void* d_ws, size_t ws_size,
                              hipStream_t stream) {
  (void)in_sizes; (void)n_in; (void)out_size;
  const float* inp  = (const float*)d_in[0];
  const float* w    = (const float*)d_in[1];
  const float* bias = (const float*)d_in[2];
  float* out = (float*)d_out;

  const size_t needA = (size_t)N_ROWS * IN_F * sizeof(unsigned short);  // 32 MiB
  const size_t needH = (size_t)IN_F * OUT_F * sizeof(unsigned short);   //  8 MiB
  if (ws_size < needA + needH) {
    k_naive<<<(N_ROWS * OUT_F) / 256, 256, 0, stream>>>(inp, w, bias, out);
    return;
  }

  unsigned short* Ab = (unsigned short*)d_ws;
  unsigned short* Ht = Ab + (size_t)N_ROWS * IN_F;

  k_convertA<<<(N_ROWS * IN_F) / (8 * 256), 256, 0, stream>>>(inp, Ab);
  k_buildHt<<<(IN_F * OUT_F) / (8 * 256), 256, 0, stream>>>(w, Ht);
  k_gemm<<<NWG, 256, 0, stream>>>(Ab, Ht, bias, out);
}

// Round 2
// 101.619 us; speedup vs baseline: 1.2853x; 1.2853x over previous
//
#include <hip/hip_runtime.h>
#include <stdint.h>

#define IN_F 2048
#define OUT_F 2048
#define N_ROWS 8192

// ---- GEMM geometry: 256x256 tile, BK=32, 8 waves (2Mx4N), 4-deep LDS pipeline
#define BM 256
#define BN 256
#define BK 32
#define NT (IN_F / BK)             // 64 K-tiles
#define TM_TILES (N_ROWS / BM)     // 32
#define TN_TILES (OUT_F / BN)      // 8
#define NWG (TM_TILES * TN_TILES)  // 256 == #CUs
#define TILE_SHORTS (BM * BK)      // 8192 shorts = 16 KiB
#define BUF_SHORTS (2 * TILE_SHORTS)

typedef __bf16 bf16x8 __attribute__((ext_vector_type(8)));
typedef float f32x4 __attribute__((ext_vector_type(4)));
typedef unsigned short ushortx8 __attribute__((ext_vector_type(8)));

// fp32 -> bf16 bits, round-to-nearest-even
__device__ __forceinline__ unsigned short f2bf(float f) {
  unsigned u = __builtin_bit_cast(unsigned, f);
  u += 0x7FFFu + ((u >> 16) & 1u);
  return (unsigned short)(u >> 16);
}

// async global->LDS, 16B/lane. LDS dest is wave-uniform base + lane*16.
__device__ __forceinline__ void async16(void* lds, const void* g) {
  __builtin_amdgcn_global_load_lds(
      (const __attribute__((address_space(1))) void*)(uintptr_t)g,
      (__attribute__((address_space(3))) void*)(uint32_t)(uintptr_t)lds,
      16, 0, 0);
}

// ---- prep 1: A fp32 -> bf16 bits ----
__global__ __launch_bounds__(256) void k_convertA(const float* __restrict__ A,
                                                  unsigned short* __restrict__ Ab) {
  const size_t t = (size_t)blockIdx.x * 256 + threadIdx.x;
  const float4* a4 = reinterpret_cast<const float4*>(A);
  float4 v0 = a4[2 * t];
  float4 v1 = a4[2 * t + 1];
  ushortx8 o;
  o[0] = f2bf(v0.x); o[1] = f2bf(v0.y); o[2] = f2bf(v0.z); o[3] = f2bf(v0.w);
  o[4] = f2bf(v1.x); o[5] = f2bf(v1.y); o[6] = f2bf(v1.z); o[7] = f2bf(v1.w);
  *reinterpret_cast<ushortx8*>(Ab + t * 8) = o;
}

// ---- prep 2: Ht[b][a] = H_perm[a][b] = s(q,c) * W[u][(q^c)*512 + v] ----
__global__ __launch_bounds__(256) void k_buildHt(const float* __restrict__ W,
                                                 unsigned short* __restrict__ Ht) {
  const int t = blockIdx.x * 256 + threadIdx.x;
  const int b = t >> 8;
  const int a0 = (t & 255) << 3;
  const int c = b & 3, v = b >> 2;
  ushortx8 o;
#pragma unroll
  for (int e = 0; e < 8; ++e) {
    const int a = a0 + e;
    const int q = a & 3, u = a >> 2;
    float w = W[(size_t)u * OUT_F + ((q ^ c) << 9) + v];
    if ((0x284E >> ((q << 2) | c)) & 1) w = -w;
    o[e] = f2bf(w);
  }
  *reinterpret_cast<ushortx8*>(Ht + (size_t)b * IN_F + a0) = o;
}

// ---- main GEMM: C = A(bf16) @ Ht^T + bias ----
__global__ __launch_bounds__(512, 2) void k_gemm(const unsigned short* __restrict__ A,
                                                 const unsigned short* __restrict__ Bt,
                                                 const float* __restrict__ bias,
                                                 float* __restrict__ C) {
  __shared__ __align__(16) unsigned short lds[4 * BUF_SHORTS];  // 128 KiB

  const int tid = threadIdx.x;
  const int lane = tid & 63;
  const int w = tid >> 6;   // wave 0..7
  const int wm = w >> 2;    // 0..1 -> rows wm*128..+128
  const int wn = w & 3;     // 0..3 -> cols wn*64..+64
  const int fr = lane & 15;
  const int g = lane >> 4;  // k-group 0..3 (8 bf16 each)

  // XCD-bijective swizzle: 256 wgs, 32 contiguous tiles per XCD
  const int wg = blockIdx.x;
  const int swz = (wg & 7) * (NWG >> 3) + (wg >> 3);
  const int tm = swz >> 3;
  const int tn = swz & 7;
  const int row0 = tm * BM, col0 = tn * BN;

  // ---- staging descriptors: per wave 2 A-pieces + 2 B-pieces per tile ----
  // chunk index t in [0,1024): row r=t>>2, 16B slot s=t&3.
  // T2 swizzle, write side: slot s holds global k-group ga = s ^ ((r>>1)&3)
  // (pre-swizzled GLOBAL source, linear LDS dest -> rule #21 compliant).
  const unsigned short* srcA[2];
  const unsigned short* srcB[2];
  int tOff[2];
#pragma unroll
  for (int i = 0; i < 2; ++i) {
    const int t = w * 128 + i * 64 + lane;
    const int r = t >> 2, s = t & 3;
    const int ga = s ^ ((r >> 1) & 3);
    srcA[i] = A + (size_t)(row0 + r) * IN_F + ga * 8;
    srcB[i] = Bt + (size_t)(col0 + r) * IN_F + ga * 8;
    tOff[i] = t * 8;  // shorts
  }

#define STAGE(T)                                              \
  do {                                                        \
    unsigned short* base_ = &lds[((T) & 3) * BUF_SHORTS];     \
    const int ko_ = (T) * BK;                                 \
    async16(base_ + tOff[0], srcA[0] + ko_);                  \
    async16(base_ + tOff[1], srcA[1] + ko_);                  \
    async16(base_ + TILE_SHORTS + tOff[0], srcB[0] + ko_);    \
    async16(base_ + TILE_SHORTS + tOff[1], srcB[1] + ko_);    \
  } while (0)

  // ---- fragment read offsets (shorts), read-side swizzle matches write side
  int offA[8], offB[4];
#pragma unroll
  for (int m = 0; m < 8; ++m) {
    const int r = wm * 128 + m * 16 + fr;
    offA[m] = r * BK + (g ^ ((r >> 1) & 3)) * 8;
  }
#pragma unroll
  for (int n = 0; n < 4; ++n) {
    const int r = wn * 64 + n * 16 + fr;
    offB[n] = r * BK + (g ^ ((r >> 1) & 3)) * 8;
  }

  f32x4 acc[8][4] = {};

  // prologue: 3 tiles in flight (12 loads/wave)
  STAGE(0);
  STAGE(1);
  STAGE(2);

  // Per tile: vmcnt(N) [own stage of tile T retired] -> barrier [everyone's
  // retired; also: all waves done reading buf[(T-1)%4]] -> ds_read frags ->
  // STAGE(T+3) into buf[(T-1)%4] (safe: post-barrier) -> MFMA.
#define TILE(T, VMSTR, DOSTAGE)                                               \
  do {                                                                        \
    asm volatile("s_waitcnt vmcnt(" VMSTR ")" ::: "memory");                  \
    __builtin_amdgcn_s_barrier();                                             \
    __builtin_amdgcn_sched_barrier(0);                                        \
    const unsigned short* ab_ = &lds[((T) & 3) * BUF_SHORTS];                 \
    const unsigned short* bb_ = ab_ + TILE_SHORTS;                            \
    bf16x8 af[8], bg[4];                                                      \
    _Pragma("unroll") for (int m = 0; m < 8; ++m)                             \
        af[m] = __builtin_bit_cast(                                           \
            bf16x8, *reinterpret_cast<const ushortx8*>(ab_ + offA[m]));       \
    _Pragma("unroll") for (int n = 0; n < 4; ++n)                             \
        bg[n] = __builtin_bit_cast(                                           \
            bf16x8, *reinterpret_cast<const ushortx8*>(bb_ + offB[n]));       \
    if (DOSTAGE) STAGE((T) + 3);                                              \
    __builtin_amdgcn_s_setprio(1);                                            \
    _Pragma("unroll") for (int m = 0; m < 8; ++m)                             \
        _Pragma("unroll") for (int n = 0; n < 4; ++n)                         \
            acc[m][n] = __builtin_amdgcn_mfma_f32_16x16x32_bf16(              \
                af[m], bg[n], acc[m][n], 0, 0, 0);                            \
    __builtin_amdgcn_s_setprio(0);                                            \
  } while (0)

  for (int t = 0; t < NT - 3; ++t) {
    TILE(t, "8", true);
  }
  TILE(NT - 3, "8", false);
  TILE(NT - 2, "4", false);
  TILE(NT - 1, "0", false);

#undef TILE
#undef STAGE

  // ---- epilogue: C/D layout col=lane&15, row=(lane>>4)*4+reg ----
  const int g4 = g << 2;
  float bv[4];
#pragma unroll
  for (int n = 0; n < 4; ++n) bv[n] = bias[col0 + wn * 64 + n * 16 + fr];
#pragma unroll
  for (int m = 0; m < 8; ++m) {
#pragma unroll
    for (int e = 0; e < 4; ++e) {
      const int row = row0 + wm * 128 + m * 16 + g4 + e;
      float* cp = C + (size_t)row * OUT_F + col0 + wn * 64 + fr;
#pragma unroll
      for (int n = 0; n < 4; ++n) cp[n * 16] = acc[m][n][e] + bv[n];
    }
  }
}

// ---- fallback if workspace too small: naive fp32 ----
__global__ __launch_bounds__(256) void k_naive(const float* __restrict__ A,
                                               const float* __restrict__ W,
                                               const float* __restrict__ bias,
                                               float* __restrict__ C) {
  const int idx = blockIdx.x * 256 + threadIdx.x;
  const int m = idx >> 11;
  const int b = idx & (OUT_F - 1);
  const int c = b & 3, v = b >> 2;
  float acc = 0.f;
  const float* arow = A + (size_t)m * IN_F;
  for (int a = 0; a < IN_F; ++a) {
    const int q = a & 3, u = a >> 2;
    float h = W[(size_t)u * OUT_F + ((q ^ c) << 9) + v];
    if ((0x284E >> ((q << 2) | c)) & 1) h = -h;
    acc += arow[a] * h;
  }
  C[idx] = acc + bias[b];
}

extern "C" void kernel_launch(void* const* d_in, const int* in_sizes, int n_in,
                              void* d_out, int out_size, void* d_ws, size_t ws_size,
                              hipStream_t stream) {
  (void)in_sizes; (void)n_in; (void)out_size;
  const float* inp  = (const float*)d_in[0];
  const float* w    = (const float*)d_in[1];
  const float* bias = (const float*)d_in[2];
  float* out = (float*)d_out;

  const size_t needA = (size_t)N_ROWS * IN_F * sizeof(unsigned short);  // 32 MiB
  const size_t needH = (size_t)IN_F * OUT_F * sizeof(unsigned short);   //  8 MiB
  if (ws_size < needA + needH) {
    k_naive<<<(N_ROWS * OUT_F) / 256, 256, 0, stream>>>(inp, w, bias, out);
    return;
  }

  unsigned short* Ab = (unsigned short*)d_ws;
  unsigned short* Ht = Ab + (size_t)N_ROWS * IN_F;

  k_convertA<<<(N_ROWS * IN_F) / (8 * 256), 256, 0, stream>>>(inp, Ab);
  k_buildHt<<<(IN_F * OUT_F) / (8 * 256), 256, 0, stream>>>(w, Ht);
  k_gemm<<<NWG, 512, 0, stream>>>(Ab, Ht, bias, out);
}

// Round 3
// 100.392 us; speedup vs baseline: 1.3010x; 1.0122x over previous
//
#include <hip/hip_runtime.h>
#include <stdint.h>

#define IN_F 2048
#define OUT_F 2048
#define N_ROWS 8192

// ---- GEMM geometry: 256x256 tile, BK=32, 8 waves (2Mx4N), 4-deep LDS pipeline
#define BM 256
#define BN 256
#define BK 32
#define NT (IN_F / BK)             // 64 K-tiles
#define TM_TILES (N_ROWS / BM)     // 32
#define TN_TILES (OUT_F / BN)      // 8
#define NWG (TM_TILES * TN_TILES)  // 256 == #CUs
#define TILE_SHORTS (BM * BK)      // 8192 shorts = 16 KiB
#define BUF_SHORTS (2 * TILE_SHORTS)

typedef __bf16 bf16x8 __attribute__((ext_vector_type(8)));
typedef float f32x4 __attribute__((ext_vector_type(4)));
typedef unsigned short ushortx8 __attribute__((ext_vector_type(8)));

// fp32 -> bf16 bits, round-to-nearest-even
__device__ __forceinline__ unsigned short f2bf(float f) {
  unsigned u = __builtin_bit_cast(unsigned, f);
  u += 0x7FFFu + ((u >> 16) & 1u);
  return (unsigned short)(u >> 16);
}

// async global->LDS, 16B/lane. LDS dest is wave-uniform base + lane*16.
__device__ __forceinline__ void async16(void* lds, const void* g) {
  __builtin_amdgcn_global_load_lds(
      (const __attribute__((address_space(1))) void*)(uintptr_t)g,
      (__attribute__((address_space(3))) void*)(uint32_t)(uintptr_t)lds,
      16, 0, 0);
}

__device__ __forceinline__ bf16x8 ld8(const unsigned short* p) {
  return __builtin_bit_cast(bf16x8, *reinterpret_cast<const ushortx8*>(p));
}

// ---- prep 1: A fp32 -> bf16 bits ----
__global__ __launch_bounds__(256) void k_convertA(const float* __restrict__ A,
                                                  unsigned short* __restrict__ Ab) {
  const size_t t = (size_t)blockIdx.x * 256 + threadIdx.x;
  const float4* a4 = reinterpret_cast<const float4*>(A);
  float4 v0 = a4[2 * t];
  float4 v1 = a4[2 * t + 1];
  ushortx8 o;
  o[0] = f2bf(v0.x); o[1] = f2bf(v0.y); o[2] = f2bf(v0.z); o[3] = f2bf(v0.w);
  o[4] = f2bf(v1.x); o[5] = f2bf(v1.y); o[6] = f2bf(v1.z); o[7] = f2bf(v1.w);
  *reinterpret_cast<ushortx8*>(Ab + t * 8) = o;
}

// ---- prep 2: Ht[b][a] = H_perm[a][b] = s(q,c) * W[u][(q^c)*512 + v] ----
__global__ __launch_bounds__(256) void k_buildHt(const float* __restrict__ W,
                                                 unsigned short* __restrict__ Ht) {
  const int t = blockIdx.x * 256 + threadIdx.x;
  const int b = t >> 8;
  const int a0 = (t & 255) << 3;
  const int c = b & 3, v = b >> 2;
  ushortx8 o;
#pragma unroll
  for (int e = 0; e < 8; ++e) {
    const int a = a0 + e;
    const int q = a & 3, u = a >> 2;
    float w = W[(size_t)u * OUT_F + ((q ^ c) << 9) + v];
    if ((0x284E >> ((q << 2) | c)) & 1) w = -w;
    o[e] = f2bf(w);
  }
  *reinterpret_cast<ushortx8*>(Ht + (size_t)b * IN_F + a0) = o;
}

// ---- main GEMM: C = A(bf16) @ Ht^T + bias ----
__global__ __launch_bounds__(512, 2) void k_gemm(const unsigned short* __restrict__ A,
                                                 const unsigned short* __restrict__ Bt,
                                                 const float* __restrict__ bias,
                                                 float* __restrict__ C) {
  __shared__ __align__(16) unsigned short lds[4 * BUF_SHORTS];  // 128 KiB

  const int tid = threadIdx.x;
  const int lane = tid & 63;
  const int w = tid >> 6;   // wave 0..7
  const int wm = w >> 2;    // 0..1 -> rows wm*128..+128
  const int wn = w & 3;     // 0..3 -> cols wn*64..+64
  const int fr = lane & 15;
  const int g = lane >> 4;  // k-group 0..3 (8 bf16 each)

  // XCD-bijective swizzle: 256 wgs, 32 contiguous tiles per XCD
  const int wg = blockIdx.x;
  const int swz = (wg & 7) * (NWG >> 3) + (wg >> 3);
  const int tm = swz >> 3;
  const int tn = swz & 7;
  const int row0 = tm * BM, col0 = tn * BN;

  // ---- staging descriptors: per wave 2 A-pieces + 2 B-pieces per tile ----
  // chunk index t in [0,1024): row r=t>>2, 16B slot s=t&3.
  // T2 swizzle, write side: slot s holds global k-group ga = s ^ ((r>>1)&3)
  // (pre-swizzled GLOBAL source, linear LDS dest).
  const unsigned short* srcA[2];
  const unsigned short* srcB[2];
  int tOff[2];
#pragma unroll
  for (int i = 0; i < 2; ++i) {
    const int t = w * 128 + i * 64 + lane;
    const int r = t >> 2, s = t & 3;
    const int ga = s ^ ((r >> 1) & 3);
    srcA[i] = A + (size_t)(row0 + r) * IN_F + ga * 8;
    srcB[i] = Bt + (size_t)(col0 + r) * IN_F + ga * 8;
    tOff[i] = t * 8;  // shorts
  }

#define STAGE(T)                                              \
  do {                                                        \
    unsigned short* base_ = &lds[((T) & 3) * BUF_SHORTS];     \
    const int ko_ = (T) * BK;                                 \
    async16(base_ + tOff[0], srcA[0] + ko_);                  \
    async16(base_ + tOff[1], srcA[1] + ko_);                  \
    async16(base_ + TILE_SHORTS + tOff[0], srcB[0] + ko_);    \
    async16(base_ + TILE_SHORTS + tOff[1], srcB[1] + ko_);    \
  } while (0)

  // ---- fragment read offsets (shorts), read-side swizzle matches write side
  int offA[8], offB[4];
#pragma unroll
  for (int m = 0; m < 8; ++m) {
    const int r = wm * 128 + m * 16 + fr;
    offA[m] = r * BK + (g ^ ((r >> 1) & 3)) * 8;
  }
#pragma unroll
  for (int n = 0; n < 4; ++n) {
    const int r = wn * 64 + n * 16 + fr;
    offB[n] = r * BK + (g ^ ((r >> 1) & 3)) * 8;
  }

  f32x4 acc[8][4] = {};

#define MFMA_(a_, b_, c_) __builtin_amdgcn_mfma_f32_16x16x32_bf16(a_, b_, c_, 0, 0, 0)

  // prologue: 3 tiles in flight (12 loads/wave)
  STAGE(0);
  STAGE(1);
  STAGE(2);

  // Per tile: vmcnt(N) [own stage of tile T retired] -> barrier [everyone's
  // retired; all waves done reading buf[(T-1)%4]] -> phased {ds_read || MFMA}:
  // reads for cluster p+1 overlap cluster p's MFMAs (counted lgkmcnt).
#define TILE(T, VMSTR, DOSTAGE)                                               \
  do {                                                                        \
    asm volatile("s_waitcnt vmcnt(" VMSTR ")" ::: "memory");                  \
    __builtin_amdgcn_s_barrier();                                             \
    __builtin_amdgcn_sched_barrier(0);                                        \
    const unsigned short* ab_ = &lds[((T) & 3) * BUF_SHORTS];                 \
    const unsigned short* bb_ = ab_ + TILE_SHORTS;                            \
    bf16x8 bg[4];                                                             \
    _Pragma("unroll") for (int n = 0; n < 4; ++n) bg[n] = ld8(bb_ + offB[n]); \
    bf16x8 a0 = ld8(ab_ + offA[0]), a1 = ld8(ab_ + offA[1]);                  \
    if (DOSTAGE) STAGE((T) + 3);                                              \
    bf16x8 a2 = ld8(ab_ + offA[2]), a3 = ld8(ab_ + offA[3]);                  \
    __builtin_amdgcn_s_setprio(1);                                            \
    _Pragma("unroll") for (int n = 0; n < 4; ++n) {                           \
      acc[0][n] = MFMA_(a0, bg[n], acc[0][n]);                                \
      acc[1][n] = MFMA_(a1, bg[n], acc[1][n]);                                \
    }                                                                         \
    __builtin_amdgcn_s_setprio(0);                                            \
    bf16x8 a4 = ld8(ab_ + offA[4]), a5 = ld8(ab_ + offA[5]);                  \
    __builtin_amdgcn_s_setprio(1);                                            \
    _Pragma("unroll") for (int n = 0; n < 4; ++n) {                           \
      acc[2][n] = MFMA_(a2, bg[n], acc[2][n]);                                \
      acc[3][n] = MFMA_(a3, bg[n], acc[3][n]);                                \
    }                                                                         \
    __builtin_amdgcn_s_setprio(0);                                            \
    bf16x8 a6 = ld8(ab_ + offA[6]), a7 = ld8(ab_ + offA[7]);                  \
    __builtin_amdgcn_s_setprio(1);                                            \
    _Pragma("unroll") for (int n = 0; n < 4; ++n) {                           \
      acc[4][n] = MFMA_(a4, bg[n], acc[4][n]);                                \
      acc[5][n] = MFMA_(a5, bg[n], acc[5][n]);                                \
    }                                                                         \
    _Pragma("unroll") for (int n = 0; n < 4; ++n) {                           \
      acc[6][n] = MFMA_(a6, bg[n], acc[6][n]);                                \
      acc[7][n] = MFMA_(a7, bg[n], acc[7][n]);                                \
    }                                                                         \
    __builtin_amdgcn_s_setprio(0);                                            \
  } while (0)

  for (int t = 0; t < NT - 3; ++t) {
    TILE(t, "8", true);
  }
  TILE(NT - 3, "8", false);
  TILE(NT - 2, "4", false);
  TILE(NT - 1, "0", false);

#undef TILE
#undef STAGE

  // ---- epilogue: C/D layout col=lane&15, row=(lane>>4)*4+reg ----
  const int g4 = g << 2;
  float bv[4];
#pragma unroll
  for (int n = 0; n < 4; ++n) bv[n] = bias[col0 + wn * 64 + n * 16 + fr];
#pragma unroll
  for (int m = 0; m < 8; ++m) {
#pragma unroll
    for (int e = 0; e < 4; ++e) {
      const int row = row0 + wm * 128 + m * 16 + g4 + e;
      float* cp = C + (size_t)row * OUT_F + col0 + wn * 64 + fr;
#pragma unroll
      for (int n = 0; n < 4; ++n) cp[n * 16] = acc[m][n][e] + bv[n];
    }
  }
}

// ---- fallback if workspace too small: naive fp32 ----
__global__ __launch_bounds__(256) void k_naive(const float* __restrict__ A,
                                               const float* __restrict__ W,
                                               const float* __restrict__ bias,
                                               float* __restrict__ C) {
  const int idx = blockIdx.x * 256 + threadIdx.x;
  const int m = idx >> 11;
  const int b = idx & (OUT_F - 1);
  const int c = b & 3, v = b >> 2;
  float acc = 0.f;
  const float* arow = A + (size_t)m * IN_F;
  for (int a = 0; a < IN_F; ++a) {
    const int q = a & 3, u = a >> 2;
    float h = W[(size_t)u * OUT_F + ((q ^ c) << 9) + v];
    if ((0x284E >> ((q << 2) | c)) & 1) h = -h;
    acc += arow[a] * h;
  }
  C[idx] = acc + bias[b];
}

extern "C" void kernel_launch(void* const* d_in, const int* in_sizes, int n_in,
                              void* d_out, int out_size, void* d_ws, size_t ws_size,
                              hipStream_t stream) {
  (void)in_sizes; (void)n_in; (void)out_size;
  const float* inp  = (const float*)d_in[0];
  const float* w    = (const float*)d_in[1];
  const float* bias = (const float*)d_in[2];
  float* out = (float*)d_out;

  const size_t needA = (size_t)N_ROWS * IN_F * sizeof(unsigned short);  // 32 MiB
  const size_t needH = (size_t)IN_F * OUT_F * sizeof(unsigned short);   //  8 MiB
  if (ws_size < needA + needH) {
    k_naive<<<(N_ROWS * OUT_F) / 256, 256, 0, stream>>>(inp, w, bias, out);
    return;
  }

  unsigned short* Ab = (unsigned short*)d_ws;
  unsigned short* Ht = Ab + (size_t)N_ROWS * IN_F;

  k_convertA<<<(N_ROWS * IN_F) / (8 * 256), 256, 0, stream>>>(inp, Ab);
  k_buildHt<<<(IN_F * OUT_F) / (8 * 256), 256, 0, stream>>>(w, Ht);
  k_gemm<<<NWG, 512, 0, stream>>>(Ab, Ht, bias, out);
}

// Round 4
// 97.149 us; speedup vs baseline: 1.3444x; 1.0334x over previous
//
#include <hip/hip_runtime.h>
#include <stdint.h>

#define IN_F 2048
#define OUT_F 2048
#define N_ROWS 8192

// ---- GEMM geometry: 256x256 tile, BK=32, 8 waves (2Mx4N), 4-deep LDS pipeline
#define BM 256
#define BN 256
#define BK 32
#define NT (IN_F / BK)             // 64 K-tiles
#define TM_TILES (N_ROWS / BM)     // 32
#define TN_TILES (OUT_F / BN)      // 8
#define NWG (TM_TILES * TN_TILES)  // 256 == #CUs
#define TILE_SHORTS (BM * BK)      // 8192 shorts = 16 KiB
#define BUF_SHORTS (2 * TILE_SHORTS)

typedef __bf16 bf16x8 __attribute__((ext_vector_type(8)));
typedef float f32x4 __attribute__((ext_vector_type(4)));
typedef unsigned short ushortx8 __attribute__((ext_vector_type(8)));

// fp32 -> bf16 bits, round-to-nearest-even
__device__ __forceinline__ unsigned short f2bf(float f) {
  unsigned u = __builtin_bit_cast(unsigned, f);
  u += 0x7FFFu + ((u >> 16) & 1u);
  return (unsigned short)(u >> 16);
}

// async global->LDS, 16B/lane. LDS dest is wave-uniform base + lane*16.
__device__ __forceinline__ void async16(void* lds, const void* g) {
  __builtin_amdgcn_global_load_lds(
      (const __attribute__((address_space(1))) void*)(uintptr_t)g,
      (__attribute__((address_space(3))) void*)(uint32_t)(uintptr_t)lds,
      16, 0, 0);
}

__device__ __forceinline__ bf16x8 ld8(const unsigned short* p) {
  return __builtin_bit_cast(bf16x8, *reinterpret_cast<const ushortx8*>(p));
}

// ---- fused prep: blocks [0,8192) convert A fp32->bf16; [8192,10240) build Ht
__global__ __launch_bounds__(256) void k_prep(const float* __restrict__ A,
                                              unsigned short* __restrict__ Ab,
                                              const float* __restrict__ W,
                                              unsigned short* __restrict__ Ht) {
  const int bid = blockIdx.x;
  if (bid < 8192) {
    const size_t t = (size_t)bid * 256 + threadIdx.x;
    const float4* a4 = reinterpret_cast<const float4*>(A);
    float4 v0 = a4[2 * t];
    float4 v1 = a4[2 * t + 1];
    ushortx8 o;
    o[0] = f2bf(v0.x); o[1] = f2bf(v0.y); o[2] = f2bf(v0.z); o[3] = f2bf(v0.w);
    o[4] = f2bf(v1.x); o[5] = f2bf(v1.y); o[6] = f2bf(v1.z); o[7] = f2bf(v1.w);
    *reinterpret_cast<ushortx8*>(Ab + t * 8) = o;
  } else {
    // Ht[b][a] = H_perm[a][b] = s(q,c) * W[u][(q^c)*512 + v]
    const int t = (bid - 8192) * 256 + threadIdx.x;
    const int b = t >> 8;
    const int a0 = (t & 255) << 3;
    const int c = b & 3, v = b >> 2;
    ushortx8 o;
#pragma unroll
    for (int e = 0; e < 8; ++e) {
      const int a = a0 + e;
      const int q = a & 3, u = a >> 2;
      float w = W[(size_t)u * OUT_F + ((q ^ c) << 9) + v];
      if ((0x284E >> ((q << 2) | c)) & 1) w = -w;
      o[e] = f2bf(w);
    }
    *reinterpret_cast<ushortx8*>(Ht + (size_t)b * IN_F + a0) = o;
  }
}

// ---- main GEMM: C = A(bf16) @ Ht^T + bias ----
__global__ __launch_bounds__(512, 2) void k_gemm(const unsigned short* __restrict__ A,
                                                 const unsigned short* __restrict__ Bt,
                                                 const float* __restrict__ bias,
                                                 float* __restrict__ C) {
  __shared__ __align__(16) unsigned short lds[4 * BUF_SHORTS];  // 128 KiB

  const int tid = threadIdx.x;
  const int lane = tid & 63;
  const int w = tid >> 6;   // wave 0..7
  const int wm = w >> 2;    // 0..1 -> rows wm*128..+128
  const int wn = w & 3;     // 0..3 -> cols wn*64..+64
  const int fr = lane & 15;
  const int g = lane >> 4;  // k-group 0..3 (8 bf16 each)

  // XCD-bijective swizzle: 256 wgs, 32 contiguous tiles per XCD
  const int wg = blockIdx.x;
  const int swz = (wg & 7) * (NWG >> 3) + (wg >> 3);
  const int tm = swz >> 3;
  const int tn = swz & 7;
  const int row0 = tm * BM, col0 = tn * BN;

  // ---- staging: chunk t in [0,1024): row r=t>>2, 16B slot s=t&3.
  // T2 swizzle write side: slot s holds global k-group ga = s ^ ((r>>1)&3)
  // (pre-swizzled GLOBAL source, linear LDS dest).
  const unsigned short* srcA[2];
  const unsigned short* srcB[2];
  int tOff[2];
#pragma unroll
  for (int i = 0; i < 2; ++i) {
    const int t = w * 128 + i * 64 + lane;
    const int r = t >> 2, s = t & 3;
    const int ga = s ^ ((r >> 1) & 3);
    srcA[i] = A + (size_t)(row0 + r) * IN_F + ga * 8;
    srcB[i] = Bt + (size_t)(col0 + r) * IN_F + ga * 8;
    tOff[i] = t * 8;  // shorts
  }

#define STAGE(T)                                              \
  do {                                                        \
    unsigned short* base_ = &lds[((T) & 3) * BUF_SHORTS];     \
    const int ko_ = (T) * BK;                                 \
    async16(base_ + tOff[0], srcA[0] + ko_);                  \
    async16(base_ + tOff[1], srcA[1] + ko_);                  \
    async16(base_ + TILE_SHORTS + tOff[0], srcB[0] + ko_);    \
    async16(base_ + TILE_SHORTS + tOff[1], srcB[1] + ko_);    \
  } while (0)

  // ---- fragment read offsets (shorts), read-side swizzle matches write side
  int offA[8], offB[4];
#pragma unroll
  for (int m = 0; m < 8; ++m) {
    const int r = wm * 128 + m * 16 + fr;
    offA[m] = r * BK + (g ^ ((r >> 1) & 3)) * 8;
  }
#pragma unroll
  for (int n = 0; n < 4; ++n) {
    const int r = wn * 64 + n * 16 + fr;
    offB[n] = r * BK + (g ^ ((r >> 1) & 3)) * 8;
  }

  f32x4 acc[8][4] = {};

#define MFMA_(a_, b_, c_) __builtin_amdgcn_mfma_f32_16x16x32_bf16(a_, b_, c_, 0, 0, 0)
#define FENCE_ __builtin_amdgcn_sched_barrier(0)

  // prologue: 3 tiles in flight (12 loads/wave)
  STAGE(0);
  STAGE(1);
  STAGE(2);

  // Per tile: vmcnt(N) -> barrier -> [P0 reads: B all + A m0-3 | STAGE(T+3) |
  // P1 reads: A m4-7] -> fence -> MFMA P0 (auto lgkmcnt(4)) -> fence ->
  // MFMA P1 (auto lgkmcnt(0)). Fences pin the read/MFMA phase structure.
#define TILE(T, VMSTR, DOSTAGE)                                               \
  do {                                                                        \
    asm volatile("s_waitcnt vmcnt(" VMSTR ")" ::: "memory");                  \
    __builtin_amdgcn_s_barrier();                                             \
    FENCE_;                                                                   \
    const unsigned short* ab_ = &lds[((T) & 3) * BUF_SHORTS];                 \
    const unsigned short* bb_ = ab_ + TILE_SHORTS;                            \
    bf16x8 bg[4], af0[4], af1[4];                                             \
    _Pragma("unroll") for (int n = 0; n < 4; ++n) bg[n] = ld8(bb_ + offB[n]); \
    _Pragma("unroll") for (int m = 0; m < 4; ++m) af0[m] = ld8(ab_ + offA[m]);\
    FENCE_;                                                                   \
    if (DOSTAGE) STAGE((T) + 3);                                              \
    _Pragma("unroll") for (int m = 0; m < 4; ++m)                             \
        af1[m] = ld8(ab_ + offA[4 + m]);                                      \
    FENCE_;                                                                   \
    __builtin_amdgcn_s_setprio(1);                                            \
    _Pragma("unroll") for (int n = 0; n < 4; ++n)                             \
        _Pragma("unroll") for (int m = 0; m < 4; ++m)                         \
            acc[m][n] = MFMA_(af0[m], bg[n], acc[m][n]);                      \
    __builtin_amdgcn_s_setprio(0);                                            \
    FENCE_;                                                                   \
    __builtin_amdgcn_s_setprio(1);                                            \
    _Pragma("unroll") for (int n = 0; n < 4; ++n)                             \
        _Pragma("unroll") for (int m = 0; m < 4; ++m)                         \
            acc[4 + m][n] = MFMA_(af1[m], bg[n], acc[4 + m][n]);              \
    __builtin_amdgcn_s_setprio(0);                                            \
    FENCE_;                                                                   \
  } while (0)

  for (int t = 0; t < NT - 3; ++t) {
    TILE(t, "8", true);
  }
  TILE(NT - 3, "8", false);
  TILE(NT - 2, "4", false);
  TILE(NT - 1, "0", false);

#undef TILE
#undef STAGE

  // ---- epilogue: C/D layout col=lane&15, row=(lane>>4)*4+reg ----
  const int g4 = g << 2;
  float bv[4];
#pragma unroll
  for (int n = 0; n < 4; ++n) bv[n] = bias[col0 + wn * 64 + n * 16 + fr];
#pragma unroll
  for (int m = 0; m < 8; ++m) {
#pragma unroll
    for (int e = 0; e < 4; ++e) {
      const int row = row0 + wm * 128 + m * 16 + g4 + e;
      float* cp = C + (size_t)row * OUT_F + col0 + wn * 64 + fr;
#pragma unroll
      for (int n = 0; n < 4; ++n) cp[n * 16] = acc[m][n][e] + bv[n];
    }
  }
}

// ---- fallback if workspace too small: naive fp32 ----
__global__ __launch_bounds__(256) void k_naive(const float* __restrict__ A,
                                               const float* __restrict__ W,
                                               const float* __restrict__ bias,
                                               float* __restrict__ C) {
  const int idx = blockIdx.x * 256 + threadIdx.x;
  const int m = idx >> 11;
  const int b = idx & (OUT_F - 1);
  const int c = b & 3, v = b >> 2;
  float acc = 0.f;
  const float* arow = A + (size_t)m * IN_F;
  for (int a = 0; a < IN_F; ++a) {
    const int q = a & 3, u = a >> 2;
    float h = W[(size_t)u * OUT_F + ((q ^ c) << 9) + v];
    if ((0x284E >> ((q << 2) | c)) & 1) h = -h;
    acc += arow[a] * h;
  }
  C[idx] = acc + bias[b];
}

extern "C" void kernel_launch(void* const* d_in, const int* in_sizes, int n_in,
                              void* d_out, int out_size, void* d_ws, size_t ws_size,
                              hipStream_t stream) {
  (void)in_sizes; (void)n_in; (void)out_size;
  const float* inp  = (const float*)d_in[0];
  const float* w    = (const float*)d_in[1];
  const float* bias = (const float*)d_in[2];
  float* out = (float*)d_out;

  const size_t needA = (size_t)N_ROWS * IN_F * sizeof(unsigned short);  // 32 MiB
  const size_t needH = (size_t)IN_F * OUT_F * sizeof(unsigned short);   //  8 MiB
  if (ws_size < needA + needH) {
    k_naive<<<(N_ROWS * OUT_F) / 256, 256, 0, stream>>>(inp, w, bias, out);
    return;
  }

  unsigned short* Ab = (unsigned short*)d_ws;
  unsigned short* Ht = Ab + (size_t)N_ROWS * IN_F;

  k_prep<<<8192 + 2048, 256, 0, stream>>>(inp, Ab, w, Ht);
  k_gemm<<<NWG, 512, 0, stream>>>(Ab, Ht, bias, out);
}

// Round 5
// 94.313 us; speedup vs baseline: 1.3848x; 1.0301x over previous
//
#include <hip/hip_runtime.h>
#include <stdint.h>

#define IN_F 2048
#define OUT_F 2048
#define N_ROWS 8192

// ---- GEMM geometry: 256x256 tile, BK=64, 8 waves (2Mx4N), 8-phase schedule
#define BM 256
#define BN 256
#define BK 64
#define NT (IN_F / BK)             // 32 K-steps
#define TM_TILES (N_ROWS / BM)     // 32
#define TN_TILES (OUT_F / BN)      // 8
#define NWG (TM_TILES * TN_TILES)  // 256 == #CUs
// LDS: parity P in {0,1}: A at P*32768, B at P*32768+16384 (shorts). 128 KiB.
#define AB_STRIDE 32768
#define B_OFF 16384

typedef __bf16 bf16x8 __attribute__((ext_vector_type(8)));
typedef float f32x4 __attribute__((ext_vector_type(4)));
typedef unsigned short ushortx8 __attribute__((ext_vector_type(8)));

__device__ __forceinline__ unsigned short f2bf(float f) {
  unsigned u = __builtin_bit_cast(unsigned, f);
  u += 0x7FFFu + ((u >> 16) & 1u);
  return (unsigned short)(u >> 16);
}

__device__ __forceinline__ void async16(void* lds, const void* g) {
  __builtin_amdgcn_global_load_lds(
      (const __attribute__((address_space(1))) void*)(uintptr_t)g,
      (__attribute__((address_space(3))) void*)(uint32_t)(uintptr_t)lds,
      16, 0, 0);
}

__device__ __forceinline__ bf16x8 ld8(const unsigned short* p) {
  return __builtin_bit_cast(bf16x8, *reinterpret_cast<const ushortx8*>(p));
}

// ---- fused prep: blocks [0,8192) convert A fp32->bf16; [8192,10240) build Ht
__global__ __launch_bounds__(256) void k_prep(const float* __restrict__ A,
                                              unsigned short* __restrict__ Ab,
                                              const float* __restrict__ W,
                                              unsigned short* __restrict__ Ht) {
  const int bid = blockIdx.x;
  if (bid < 8192) {
    const size_t t = (size_t)bid * 256 + threadIdx.x;
    const float4* a4 = reinterpret_cast<const float4*>(A);
    float4 v0 = a4[2 * t];
    float4 v1 = a4[2 * t + 1];
    ushortx8 o;
    o[0] = f2bf(v0.x); o[1] = f2bf(v0.y); o[2] = f2bf(v0.z); o[3] = f2bf(v0.w);
    o[4] = f2bf(v1.x); o[5] = f2bf(v1.y); o[6] = f2bf(v1.z); o[7] = f2bf(v1.w);
    *reinterpret_cast<ushortx8*>(Ab + t * 8) = o;
  } else {
    // Ht[b][a] = H_perm[a][b] = s(q,c) * W[u][(q^c)*512 + v]
    const int t = (bid - 8192) * 256 + threadIdx.x;
    const int b = t >> 8;
    const int a0 = (t & 255) << 3;
    const int c = b & 3, v = b >> 2;
    ushortx8 o;
#pragma unroll
    for (int e = 0; e < 8; ++e) {
      const int a = a0 + e;
      const int q = a & 3, u = a >> 2;
      float w = W[(size_t)u * OUT_F + ((q ^ c) << 9) + v];
      if ((0x284E >> ((q << 2) | c)) & 1) w = -w;
      o[e] = f2bf(w);
    }
    *reinterpret_cast<ushortx8*>(Ht + (size_t)b * IN_F + a0) = o;
  }
}

// ---- main GEMM: C = A(bf16) @ Ht^T + bias. m201-style 8-phase schedule. ----
__global__ __launch_bounds__(512, 2) void k_gemm(const unsigned short* __restrict__ A,
                                                 const unsigned short* __restrict__ Bt,
                                                 const float* __restrict__ bias,
                                                 float* __restrict__ C) {
  __shared__ __align__(16) unsigned short lds[2 * AB_STRIDE];  // 128 KiB

  const int tid = threadIdx.x;
  const int lane = tid & 63;
  const int w = tid >> 6;   // wave 0..7
  const int wm = w >> 2;    // 0..1 -> rows wm*128..+128
  const int wn = w & 3;     // 0..3 -> cols wn*64..+64
  const int fr = lane & 15;
  const int g = lane >> 4;  // k-subgroup 0..3

  // XCD-bijective swizzle: 256 wgs, 32 contiguous tiles per XCD
  const int wg = blockIdx.x;
  const int swz = (wg & 7) * (NWG >> 3) + (wg >> 3);
  const int tm = swz >> 3;
  const int tn = swz & 7;
  const int row0 = tm * BM, col0 = tn * BN;

  // ---- staging: half-tile = 128 rows x 64 k = 1024 x 16B chunks; thread tid
  // handles chunks tid and tid+512. chunk c: r=c>>3 (row), s=c&7 (16B slot).
  // T2 swizzle write side: slot s holds global k-group ga = s ^ (r&7)
  // (pre-swizzled GLOBAL source, linear LDS dest). r&7 == (tid>>3)&7 for both.
  const int kgsw = (((tid & 7) ^ ((tid >> 3) & 7)) << 3);
  const unsigned short* srcA0 = A + (size_t)(row0 + (tid >> 3)) * IN_F + kgsw;
  const unsigned short* srcB0 = Bt + (size_t)(col0 + (tid >> 3)) * IN_F + kgsw;

#define STG_A(P, H, T)                                                      \
  do {                                                                      \
    unsigned short* d_ = lds + (P) * AB_STRIDE + (H) * 8192 + tid * 8;      \
    const unsigned short* s_ = srcA0 + (size_t)(H) * 128 * IN_F + (T) * BK; \
    async16(d_, s_);                                                        \
    async16(d_ + 4096, s_ + (size_t)64 * IN_F);                             \
  } while (0)
#define STG_B(P, H, T)                                                        \
  do {                                                                        \
    unsigned short* d_ = lds + (P) * AB_STRIDE + B_OFF + (H) * 8192 + tid * 8;\
    const unsigned short* s_ = srcB0 + (size_t)(H) * 128 * IN_F + (T) * BK;   \
    async16(d_, s_);                                                          \
    async16(d_ + 4096, s_ + (size_t)64 * IN_F);                               \
  } while (0)

  // ---- fragment read offsets (shorts). row&7 == fr&7 for all frags.
  // slot for k-subgroup gk at row R: (gk ^ (R&7)); gk = g + 4*kh.
  int slot[2];
#pragma unroll
  for (int kh = 0; kh < 2; ++kh) slot[kh] = (((g + 4 * kh) ^ (fr & 7)) << 3);
  int offArow[8], offBrow[4];
#pragma unroll
  for (int m = 0; m < 8; ++m) offArow[m] = (wm * 128 + m * 16 + fr) * BK;
#pragma unroll
  for (int n = 0; n < 4; ++n) offBrow[n] = (wn * 64 + n * 16 + fr) * BK;

  f32x4 acc[8][4] = {};
  bf16x8 bF[4][2], aF[2][2];

#define MFMA_(a_, b_, c_) __builtin_amdgcn_mfma_f32_16x16x32_bf16(a_, b_, c_, 0, 0, 0)
#define FENCE_ __builtin_amdgcn_sched_barrier(0)
#define BAR_ __builtin_amdgcn_s_barrier()
#define VM4_ asm volatile("s_waitcnt vmcnt(4)" ::: "memory")
#define VM0_ asm volatile("s_waitcnt vmcnt(0)" ::: "memory")

#define RD_B(P)                                                               \
  _Pragma("unroll") for (int n = 0; n < 4; ++n)                               \
    _Pragma("unroll") for (int kh = 0; kh < 2; ++kh)                          \
      bF[n][kh] = ld8(lds + (P) * AB_STRIDE + B_OFF + offBrow[n] + slot[kh]);
#define RD_A(P, M0)                                                           \
  _Pragma("unroll") for (int e = 0; e < 2; ++e)                               \
    _Pragma("unroll") for (int kh = 0; kh < 2; ++kh)                          \
      aF[e][kh] = ld8(lds + (P) * AB_STRIDE + offArow[(M0) + e] + slot[kh]);
#define DO_MFMA(M0)                                                           \
  __builtin_amdgcn_s_setprio(1);                                              \
  _Pragma("unroll") for (int kh = 0; kh < 2; ++kh)                            \
    _Pragma("unroll") for (int n = 0; n < 4; ++n) {                           \
      acc[(M0)][n] = MFMA_(aF[0][kh], bF[n][kh], acc[(M0)][n]);               \
      acc[(M0) + 1][n] = MFMA_(aF[1][kh], bF[n][kh], acc[(M0) + 1][n]);       \
    }                                                                         \
  __builtin_amdgcn_s_setprio(0)

  // ---- prologue: land A(0),B(0) into S0 and B(1) into S1.B ----
  STG_A(0, 0, 0); STG_A(0, 1, 0);
  STG_B(0, 0, 0); STG_B(0, 1, 0);
  STG_B(1, 0, 1); STG_B(1, 1, 1);
  VM0_;
  BAR_; FENCE_;

  // ---- steady iterations i=0..14: ksteps 2i (S0), 2i+1 (S1).
  // Stage ledger (region free-window -> slot): S1.A ph1-2 (A(2i+1)),
  // S0.B ph3-4 (B(2i+2)), S0.A ph5-6 (A(2i+2)), S1.B ph7-8 (B(2i+3)).
  // vmcnt(4)+barrier at ph4 confirms A(2i+1) before ph5 reads; at ph8
  // confirms B(2i+2)+A(2i+2) before next ph1 reads. Never drains to 0.
#pragma unroll 1
  for (int i = 0; i < 15; ++i) {
    const int t1 = 2 * i + 1, t2 = 2 * i + 2, t3 = 2 * i + 3;
    // ph1
    RD_B(0); RD_A(0, 0); FENCE_; STG_A(1, 0, t1); FENCE_; BAR_; FENCE_;
    DO_MFMA(0); FENCE_; BAR_; FENCE_;
    // ph2
    RD_A(0, 2); FENCE_; STG_A(1, 1, t1); FENCE_; BAR_; FENCE_;
    DO_MFMA(2); FENCE_; BAR_; FENCE_;
    // ph3
    RD_A(0, 4); FENCE_; STG_B(0, 0, t2); FENCE_; BAR_; FENCE_;
    DO_MFMA(4); FENCE_; BAR_; FENCE_;
    // ph4
    RD_A(0, 6); FENCE_; STG_B(0, 1, t2); FENCE_; BAR_; FENCE_;
    DO_MFMA(6); FENCE_; VM4_; BAR_; FENCE_;
    // ph5
    RD_B(1); RD_A(1, 0); FENCE_; STG_A(0, 0, t2); FENCE_; BAR_; FENCE_;
    DO_MFMA(0); FENCE_; BAR_; FENCE_;
    // ph6
    RD_A(1, 2); FENCE_; STG_A(0, 1, t2); FENCE_; BAR_; FENCE_;
    DO_MFMA(2); FENCE_; BAR_; FENCE_;
    // ph7
    RD_A(1, 4); FENCE_; STG_B(1, 0, t3); FENCE_; BAR_; FENCE_;
    DO_MFMA(4); FENCE_; BAR_; FENCE_;
    // ph8
    RD_A(1, 6); FENCE_; STG_B(1, 1, t3); FENCE_; BAR_; FENCE_;
    DO_MFMA(6); FENCE_; VM4_; BAR_; FENCE_;
  }

  // ---- epilogue iteration (ksteps 30,31): only A(31) left to stage ----
  {
    // ph1
    RD_B(0); RD_A(0, 0); FENCE_; STG_A(1, 0, 31); FENCE_; BAR_; FENCE_;
    DO_MFMA(0); FENCE_; BAR_; FENCE_;
    // ph2
    RD_A(0, 2); FENCE_; STG_A(1, 1, 31); FENCE_; BAR_; FENCE_;
    DO_MFMA(2); FENCE_; BAR_; FENCE_;
    // ph3
    RD_A(0, 4); FENCE_; BAR_; FENCE_;
    DO_MFMA(4); FENCE_; BAR_; FENCE_;
    // ph4
    RD_A(0, 6); FENCE_; BAR_; FENCE_;
    DO_MFMA(6); FENCE_; VM0_; BAR_; FENCE_;
    // ph5
    RD_B(1); RD_A(1, 0); FENCE_; BAR_; FENCE_;
    DO_MFMA(0); FENCE_; BAR_; FENCE_;
    // ph6
    RD_A(1, 2); FENCE_; BAR_; FENCE_;
    DO_MFMA(2); FENCE_; BAR_; FENCE_;
    // ph7
    RD_A(1, 4); FENCE_; BAR_; FENCE_;
    DO_MFMA(4); FENCE_; BAR_; FENCE_;
    // ph8
    RD_A(1, 6); FENCE_; BAR_; FENCE_;
    DO_MFMA(6); FENCE_;
  }

#undef RD_B
#undef RD_A
#undef DO_MFMA
#undef STG_A
#undef STG_B

  // ---- epilogue: C/D layout col=lane&15, row=(lane>>4)*4+reg ----
  const int g4 = g << 2;
  float bv[4];
#pragma unroll
  for (int n = 0; n < 4; ++n) bv[n] = bias[col0 + wn * 64 + n * 16 + fr];
#pragma unroll
  for (int m = 0; m < 8; ++m) {
#pragma unroll
    for (int e = 0; e < 4; ++e) {
      const int row = row0 + wm * 128 + m * 16 + g4 + e;
      float* cp = C + (size_t)row * OUT_F + col0 + wn * 64 + fr;
#pragma unroll
      for (int n = 0; n < 4; ++n) cp[n * 16] = acc[m][n][e] + bv[n];
    }
  }
}

// ---- fallback if workspace too small: naive fp32 ----
__global__ __launch_bounds__(256) void k_naive(const float* __restrict__ A,
                                               const float* __restrict__ W,
                                               const float* __restrict__ bias,
                                               float* __restrict__ C) {
  const int idx = blockIdx.x * 256 + threadIdx.x;
  const int m = idx >> 11;
  const int b = idx & (OUT_F - 1);
  const int c = b & 3, v = b >> 2;
  float acc = 0.f;
  const float* arow = A + (size_t)m * IN_F;
  for (int a = 0; a < IN_F; ++a) {
    const int q = a & 3, u = a >> 2;
    float h = W[(size_t)u * OUT_F + ((q ^ c) << 9) + v];
    if ((0x284E >> ((q << 2) | c)) & 1) h = -h;
    acc += arow[a] * h;
  }
  C[idx] = acc + bias[b];
}

extern "C" void kernel_launch(void* const* d_in, const int* in_sizes, int n_in,
                              void* d_out, int out_size, void* d_ws, size_t ws_size,
                              hipStream_t stream) {
  (void)in_sizes; (void)n_in; (void)out_size;
  const float* inp  = (const float*)d_in[0];
  const float* w    = (const float*)d_in[1];
  const float* bias = (const float*)d_in[2];
  float* out = (float*)d_out;

  const size_t needA = (size_t)N_ROWS * IN_F * sizeof(unsigned short);  // 32 MiB
  const size_t needH = (size_t)IN_F * OUT_F * sizeof(unsigned short);   //  8 MiB
  if (ws_size < needA + needH) {
    k_naive<<<(N_ROWS * OUT_F) / 256, 256, 0, stream>>>(inp, w, bias, out);
    return;
  }

  unsigned short* Ab = (unsigned short*)d_ws;
  unsigned short* Ht = Ab + (size_t)N_ROWS * IN_F;

  k_prep<<<8192 + 2048, 256, 0, stream>>>(inp, Ab, w, Ht);
  k_gemm<<<NWG, 512, 0, stream>>>(Ab, Ht, bias, out);
}